// Round 19
// baseline (416.453 us; speedup 1.0000x reference)
//
#include <hip/hip_runtime.h>
#include <hip/hip_bf16.h>

#define T_TOK 2048
#define DDIM  1024
#define NEXP  8
#define FDIM  4096
#define ROWS  (4096 + 256)

typedef __attribute__((ext_vector_type(8))) short bf16x8;
typedef __attribute__((ext_vector_type(4))) float f32x4;

#define SBW(n) ((((n) >> 3) ^ (n)) & 7)

__device__ __forceinline__ unsigned short f2b(float f) {
  union { float f; unsigned u; } v; v.f = f;
  unsigned r = v.u + 0x7FFF + ((v.u >> 16) & 1);  // RNE
  return (unsigned short)(r >> 16);
}
__device__ __forceinline__ float b2f(unsigned short s) {
  union { unsigned u; float f; } v; v.u = ((unsigned)s) << 16;
  return v.f;
}
__device__ __forceinline__ unsigned cvtpk(float lo, float hi) {
  unsigned r;
  asm("v_cvt_pk_bf16_f32 %0, %1, %2" : "=v"(r) : "v"(lo), "v"(hi));
  return r;
}
__device__ __forceinline__ void gl16(const unsigned short* g, unsigned short* l) {
  __builtin_amdgcn_global_load_lds(
      (const __attribute__((address_space(1))) unsigned int*)(const void*)g,
      (__attribute__((address_space(3))) unsigned int*)(void*)l, 16, 0, 0);
}
// pack 8 k-consecutive bf16 from column c of 8 float2 rows (R9-validated)
__device__ __forceinline__ bf16x8 pack8c(const float2* br, int c) {
  union { bf16x8 v; unsigned u[4]; } p;
  p.u[0] = cvtpk((&br[0].x)[c], (&br[1].x)[c]);
  p.u[1] = cvtpk((&br[2].x)[c], (&br[3].x)[c]);
  p.u[2] = cvtpk((&br[4].x)[c], (&br[5].x)[c]);
  p.u[3] = cvtpk((&br[6].x)[c], (&br[7].x)[c]);
  return p.v;
}

// ---------------- router (also records each token's two global slots) -------
__global__ void router_kernel(const float* __restrict__ x, const float* __restrict__ Wr,
                              int* __restrict__ cnt, int* __restrict__ tok,
                              float* __restrict__ prb, int* __restrict__ tsl) {
  int t = (blockIdx.x * blockDim.x + threadIdx.x) >> 6;
  int lane = threadIdx.x & 63;
  if (t >= T_TOK) return;
  const float* xr = x + (size_t)t * DDIM;
  float acc[NEXP];
#pragma unroll
  for (int e = 0; e < NEXP; ++e) acc[e] = 0.f;
#pragma unroll
  for (int i = 0; i < 4; ++i) {
    int d0 = lane * 16 + i * 4;
    float4 xv = *reinterpret_cast<const float4*>(xr + d0);
#pragma unroll
    for (int j = 0; j < 4; ++j) {
      float xd = (&xv.x)[j];
      float4 w0 = *reinterpret_cast<const float4*>(Wr + (size_t)(d0 + j) * NEXP);
      float4 w1 = *reinterpret_cast<const float4*>(Wr + (size_t)(d0 + j) * NEXP + 4);
      acc[0] += xd * w0.x; acc[1] += xd * w0.y; acc[2] += xd * w0.z; acc[3] += xd * w0.w;
      acc[4] += xd * w1.x; acc[5] += xd * w1.y; acc[6] += xd * w1.z; acc[7] += xd * w1.w;
    }
  }
#pragma unroll
  for (int off = 32; off >= 1; off >>= 1)
#pragma unroll
    for (int e = 0; e < NEXP; ++e) acc[e] += __shfl_down(acc[e], off);
  if (lane == 0) {
    float v0 = -1e30f, v1 = -1e30f; int i0 = 0, i1 = 0;
#pragma unroll
    for (int e = 0; e < NEXP; ++e) {
      float v = acc[e];
      if (v > v0)      { v1 = v0; i1 = i0; v0 = v; i0 = e; }
      else if (v > v1) { v1 = v; i1 = e; }
    }
    float e1 = __expf(v1 - v0);
    float p0 = 1.f / (1.f + e1);
    float p1 = e1 * p0;
    int s0 = atomicAdd(&cnt[i0], 1);
    tok[i0 * T_TOK + s0] = t; prb[i0 * T_TOK + s0] = p0;
    int s1 = atomicAdd(&cnt[i1], 1);
    tok[i1 * T_TOK + s1] = t; prb[i1 * T_TOK + s1] = p1;
    tsl[t * 2]     = i0 * T_TOK + s0;
    tsl[t * 2 + 1] = i1 * T_TOK + s1;
  }
}

// ---------------- gather+cvt: xg[off_e + s] = bf16(x[tok[e][s]]) ------------
__global__ void gather_x_kernel(const float* __restrict__ x, const int* __restrict__ cnt,
                                const int* __restrict__ tok, unsigned short* __restrict__ xg) {
  int gs = blockIdx.x * 4 + (threadIdx.x >> 6);   // global slot [0, 4096)
  int lane = threadIdx.x & 63;
  int s = gs, e = 0;
#pragma unroll
  for (int i = 0; i < NEXP - 1; ++i) {
    int c = cnt[i];
    bool go = (e == i) && (s >= c);
    if (go) { s -= c; e = i + 1; }
  }
  int tk = tok[e * T_TOK + s];
  const float* src = x + (size_t)tk * DDIM;
  unsigned short* dst = xg + (size_t)gs * DDIM;
#pragma unroll
  for (int it = 0; it < 4; ++it) {
    float4 v = *reinterpret_cast<const float4*>(src + it * 256 + lane * 4);
    uint2 p;
    p.x = cvtpk(v.x, v.y);
    p.y = cvtpk(v.z, v.w);
    *reinterpret_cast<uint2*>(dst + it * 256 + lane * 4) = p;
  }
}

// ======== fused GEMM1: act = silu(xg@W1) * (xg@W3) ========
// BN=32 (dual), LDS 24KB -> 6 blocks/CU. R18 skeleton, half-width B tile,
// float2 B-staging (8k x 2n per thread), VGPR-checked for (256,6).
__global__ __launch_bounds__(256, 6)
void gemm1ab_kernel(const unsigned short* __restrict__ xg,
                    const float* __restrict__ W1, const float* __restrict__ W3,
                    const int* __restrict__ cnt,
                    unsigned short* __restrict__ act) {
  const int e = blockIdx.z;
  const int cn = cnt[e];
  const int r0 = blockIdx.y * 128;
  if (r0 >= cn) return;
  const int n0 = blockIdx.x * 32;
  int off = 0;
#pragma unroll
  for (int i = 0; i < NEXP; ++i) off += (i < e) ? cnt[i] : 0;

  __shared__ __align__(16) unsigned short sA[128 * 64];      // 16 KB
  __shared__ __align__(16) unsigned short sB1[32 * 64];      // 4 KB
  __shared__ __align__(16) unsigned short sB3[32 * 64];      // 4 KB

  const int tid = threadIdx.x;
  const int lane = tid & 63;
  const int wid = tid >> 6;
  const int wm = wid >> 1, wn = wid & 1;

  // A staging: dense compacted rows (pre-swizzled per-lane source)
  const unsigned short* asrc[4];
#pragma unroll
  for (int i = 0; i < 4; ++i) {
    int row = (4 * wid + i) * 8 + (lane >> 3);
    int sl = (lane & 7) ^ (row & 7);
    asrc[i] = xg + (size_t)(off + r0 + row) * DDIM + sl * 8;
  }

  // B staging: tid<128 stages W1, tid>=128 stages W3; thread owns 8k x 2n.
  const int lt = tid & 127;
  const int ko = lt >> 4;            // 0..7 -> k rows 8ko..8ko+7
  const int np = (lt & 15) * 2;      // 0..30
  const float* bp = ((tid < 128) ? W1 : W3) + ((size_t)e * DDIM + 8 * ko) * FDIM + n0 + np;
  unsigned short* wb = (tid < 128) ? sB1 : sB3;
  int woff[2];
#pragma unroll
  for (int c = 0; c < 2; ++c) woff[c] = (np + c) * 64 + ((ko ^ SBW(np + c)) * 8);

  float2 br2[8];
#define LOADB1(K0)                                                              \
  _Pragma("unroll") for (int r = 0; r < 8; ++r)                                 \
      br2[r] = *reinterpret_cast<const float2*>(bp + (size_t)((K0) + r) * FDIM);
#define WRITEB1()                                                               \
  _Pragma("unroll") for (int c = 0; c < 2; ++c)                                 \
      *reinterpret_cast<bf16x8*>(wb + woff[c]) = pack8c(br2, c);
#define STAGEA1(K0)                                                             \
  _Pragma("unroll") for (int i = 0; i < 4; ++i)                                 \
      gl16(asrc[i] + (K0), &sA[(4 * wid + i) * 512]);

  f32x4 ah[4], ag[4];
#pragma unroll
  for (int m = 0; m < 4; ++m) { ah[m] = (f32x4){0,0,0,0}; ag[m] = (f32x4){0,0,0,0}; }

  LOADB1(0);

  for (int k0 = 0; k0 < DDIM; k0 += 64) {
    WRITEB1();
    STAGEA1(k0);
    __syncthreads();
    if (k0 + 64 < DDIM) LOADB1(k0 + 64);
#pragma unroll
    for (int kk = 0; kk < 2; ++kk) {
      int kc8 = kk * 4 + (lane >> 4);
      bf16x8 a[4], b1, b3;
#pragma unroll
      for (int m = 0; m < 4; ++m) {
        int row = wm * 64 + m * 16 + (lane & 15);
        a[m] = *reinterpret_cast<const bf16x8*>(&sA[row * 64 + ((kc8 ^ (row & 7)) * 8)]);
      }
      {
        int rowb = wn * 16 + (lane & 15);
        int offb = rowb * 64 + ((kc8 ^ SBW(rowb)) * 8);
        b1 = *reinterpret_cast<const bf16x8*>(&sB1[offb]);
        b3 = *reinterpret_cast<const bf16x8*>(&sB3[offb]);
      }
#pragma unroll
      for (int m = 0; m < 4; ++m) {
        ah[m] = __builtin_amdgcn_mfma_f32_16x16x32_bf16(a[m], b1, ah[m], 0, 0, 0);
        ag[m] = __builtin_amdgcn_mfma_f32_16x16x32_bf16(a[m], b3, ag[m], 0, 0, 0);
      }
    }
    __syncthreads();
  }
  // epilogue: act = silu(h) * g
#pragma unroll
  for (int m = 0; m < 4; ++m)
#pragma unroll
    for (int j = 0; j < 4; ++j) {
      int rloc = wm * 64 + m * 16 + (lane >> 4) * 4 + j;
      int s = r0 + rloc;
      if (s < cn) {
        float hv = ah[m][j];
        float gv = ag[m][j];
        float sg = hv / (1.f + __expf(-hv));
        act[(size_t)(off + s) * FDIM + n0 + wn * 16 + (lane & 15)] = f2b(sg * gv);
      }
    }
}

// ======== GEMM2p: y[sp] = act @ W2 (split-K=2, plain stores) ========
// BN=64, LDS 24KB -> 6 blocks/CU (grid-limited ~4). float2 B-staging.
__global__ __launch_bounds__(256, 6)
void gemm2p_kernel(const unsigned short* __restrict__ act, const float* __restrict__ W2,
                   const int* __restrict__ cnt,
                   float* __restrict__ y0, float* __restrict__ y1) {
  const int e = blockIdx.z >> 1;
  const int sp = blockIdx.z & 1;
  const int cn = cnt[e];
  const int r0 = blockIdx.y * 128;
  if (r0 >= cn) return;
  const int n0 = blockIdx.x * 64;
  const int kbase = sp * (FDIM / 2);
  int off = 0;
#pragma unroll
  for (int i = 0; i < NEXP; ++i) off += (i < e) ? cnt[i] : 0;

  __shared__ __align__(16) unsigned short sA[128 * 64];      // 16 KB
  __shared__ __align__(16) unsigned short sB[64 * 64];       // 8 KB

  const int tid = threadIdx.x;
  const int lane = tid & 63;
  const int wid = tid >> 6;
  const int wm = wid >> 1, wn = wid & 1;

  const unsigned short* asrc[4];
#pragma unroll
  for (int i = 0; i < 4; ++i) {
    int row = (4 * wid + i) * 8 + (lane >> 3);
    int sl = (lane & 7) ^ (row & 7);
    asrc[i] = act + (size_t)(off + r0 + row) * FDIM + kbase + sl * 8;
  }

  // B staging: all 256 threads; thread owns 8k x 2n of the 64k x 64n tile.
  const int ko = tid >> 5;           // 0..7
  const int np = (tid & 31) * 2;     // 0..62
  const float* bp = W2 + ((size_t)e * FDIM + kbase + 8 * ko) * DDIM + n0 + np;
  int woff[2];
#pragma unroll
  for (int c = 0; c < 2; ++c) woff[c] = (np + c) * 64 + ((ko ^ SBW(np + c)) * 8);

  float2 br2[8];
#define LOADB2(K0)                                                              \
  _Pragma("unroll") for (int r = 0; r < 8; ++r)                                 \
      br2[r] = *reinterpret_cast<const float2*>(bp + (size_t)((K0) + r) * DDIM);
#define WRITEB2()                                                               \
  _Pragma("unroll") for (int c = 0; c < 2; ++c)                                 \
      *reinterpret_cast<bf16x8*>(&sB[woff[c]]) = pack8c(br2, c);
#define STAGEA2(K0)                                                             \
  _Pragma("unroll") for (int i = 0; i < 4; ++i)                                 \
      gl16(asrc[i] + (K0), &sA[(4 * wid + i) * 512]);

  f32x4 acc[4][2];
#pragma unroll
  for (int m = 0; m < 4; ++m)
#pragma unroll
    for (int n = 0; n < 2; ++n) acc[m][n] = (f32x4){0,0,0,0};

  LOADB2(0);

  for (int k0 = 0; k0 < FDIM / 2; k0 += 64) {
    WRITEB2();
    STAGEA2(k0);
    __syncthreads();
    if (k0 + 64 < FDIM / 2) LOADB2(k0 + 64);
#pragma unroll
    for (int kk = 0; kk < 2; ++kk) {
      int kc8 = kk * 4 + (lane >> 4);
      bf16x8 a[4], b[2];
#pragma unroll
      for (int m = 0; m < 4; ++m) {
        int row = wm * 64 + m * 16 + (lane & 15);
        a[m] = *reinterpret_cast<const bf16x8*>(&sA[row * 64 + ((kc8 ^ (row & 7)) * 8)]);
      }
#pragma unroll
      for (int n = 0; n < 2; ++n) {
        int col = wn * 32 + n * 16 + (lane & 15);
        b[n] = *reinterpret_cast<const bf16x8*>(&sB[col * 64 + ((kc8 ^ SBW(col)) * 8)]);
      }
#pragma unroll
      for (int m = 0; m < 4; ++m)
#pragma unroll
        for (int n = 0; n < 2; ++n)
          acc[m][n] = __builtin_amdgcn_mfma_f32_16x16x32_bf16(a[m], b[n], acc[m][n], 0, 0, 0);
    }
    __syncthreads();
  }
  float* yb = (sp ? y1 : y0);
#pragma unroll
  for (int m = 0; m < 4; ++m)
#pragma unroll
    for (int j = 0; j < 4; ++j) {
      int rloc = wm * 64 + m * 16 + (lane >> 4) * 4 + j;
      int s = r0 + rloc;
      if (s < cn) {
        float* orow = yb + (size_t)(off + s) * DDIM + n0 + wn * 32 + (lane & 15);
#pragma unroll
        for (int n = 0; n < 2; ++n) orow[n * 16] = acc[m][n][j];
      }
    }
}

// ---------------- combine: out[t] = p0*(y0+y1)[g0] + p1*(y0+y1)[g1] ---------
__global__ void combine_kernel(const float* __restrict__ y0, const float* __restrict__ y1,
                               const int* __restrict__ cnt, const int* __restrict__ tsl,
                               const float* __restrict__ prb, float* __restrict__ out) {
  const int t = blockIdx.x;
  int pre[NEXP];
  pre[0] = 0;
#pragma unroll
  for (int i = 1; i < NEXP; ++i) pre[i] = pre[i - 1] + cnt[i - 1];
  int a = tsl[t * 2], b = tsl[t * 2 + 1];
  int ea = a >> 11, sa = a & (T_TOK - 1);
  int eb = b >> 11, sb = b & (T_TOK - 1);
  size_t ga = (size_t)(pre[ea] + sa) * DDIM;
  size_t gb = (size_t)(pre[eb] + sb) * DDIM;
  float pa = prb[a], pb = prb[b];
  int c = threadIdx.x * 4;
  float4 a0 = *reinterpret_cast<const float4*>(y0 + ga + c);
  float4 a1 = *reinterpret_cast<const float4*>(y1 + ga + c);
  float4 b0 = *reinterpret_cast<const float4*>(y0 + gb + c);
  float4 b1 = *reinterpret_cast<const float4*>(y1 + gb + c);
  float4 o;
  o.x = pa * (a0.x + a1.x) + pb * (b0.x + b1.x);
  o.y = pa * (a0.y + a1.y) + pb * (b0.y + b1.y);
  o.z = pa * (a0.z + a1.z) + pb * (b0.z + b1.z);
  o.w = pa * (a0.w + a1.w) + pb * (b0.w + b1.w);
  *reinterpret_cast<float4*>(out + (size_t)t * DDIM + c) = o;
}

// ============================================================================
extern "C" void kernel_launch(void* const* d_in, const int* in_sizes, int n_in,
                              void* d_out, int out_size, void* d_ws, size_t ws_size,
                              hipStream_t stream) {
  const float* x  = (const float*)d_in[0];
  const float* Wr = (const float*)d_in[1];
  const float* W1 = (const float*)d_in[2];
  const float* W2 = (const float*)d_in[3];
  const float* W3 = (const float*)d_in[4];
  float* out = (float*)d_out;

  char* ws = (char*)d_ws;
  int*   cnt = (int*)ws;                      // 32 B
  int*   tok = (int*)(ws + 1024);             // 64 KB
  float* prb = (float*)(ws + 1024 + 65536);   // 64 KB
  int*   tsl = (int*)(ws + 1024 + 2 * 65536); // 16 KB
  unsigned short* xg  = (unsigned short*)(ws + 256 * 1024);   // ROWS x DDIM bf16
  unsigned short* act = xg + (size_t)ROWS * DDIM;             // ROWS x FDIM bf16
  float* y0 = (float*)(act + (size_t)ROWS * FDIM);            // ROWS x DDIM f32
  float* y1 = y0 + (size_t)ROWS * DDIM;                       // ROWS x DDIM f32

  hipMemsetAsync(cnt, 0, NEXP * sizeof(int), stream);

  router_kernel<<<T_TOK / 4, 256, 0, stream>>>(x, Wr, cnt, tok, prb, tsl);
  gather_x_kernel<<<(2 * T_TOK) / 4, 256, 0, stream>>>(x, cnt, tok, xg);
  gemm1ab_kernel<<<dim3(FDIM / 32, 16, NEXP), 256, 0, stream>>>(xg, W1, W3, cnt, act);
  gemm2p_kernel<<<dim3(DDIM / 64, 16, NEXP * 2), 256, 0, stream>>>(act, W2, cnt, y0, y1);
  combine_kernel<<<T_TOK, 256, 0, stream>>>(y0, y1, cnt, tsl, prb, out);
}

// Round 20
// 290.175 us; speedup vs baseline: 1.4352x; 1.4352x over previous
//
#include <hip/hip_runtime.h>
#include <hip/hip_bf16.h>

#define T_TOK 2048
#define DDIM  1024
#define NEXP  8
#define FDIM  4096
#define ROWS  (4096 + 256)

typedef __attribute__((ext_vector_type(8))) short bf16x8;
typedef __attribute__((ext_vector_type(4))) float f32x4;

#define SBW(n) ((((n) >> 3) ^ (n)) & 7)

__device__ __forceinline__ unsigned short f2b(float f) {
  union { float f; unsigned u; } v; v.f = f;
  unsigned r = v.u + 0x7FFF + ((v.u >> 16) & 1);  // RNE
  return (unsigned short)(r >> 16);
}
__device__ __forceinline__ float b2f(unsigned short s) {
  union { unsigned u; float f; } v; v.u = ((unsigned)s) << 16;
  return v.f;
}
__device__ __forceinline__ unsigned cvtpk(float lo, float hi) {
  unsigned r;
  asm("v_cvt_pk_bf16_f32 %0, %1, %2" : "=v"(r) : "v"(lo), "v"(hi));
  return r;
}
__device__ __forceinline__ void gl16(const unsigned short* g, unsigned short* l) {
  __builtin_amdgcn_global_load_lds(
      (const __attribute__((address_space(1))) unsigned int*)(const void*)g,
      (__attribute__((address_space(3))) unsigned int*)(void*)l, 16, 0, 0);
}
__device__ __forceinline__ bf16x8 pack8(const float4* br, int c) {
  union { bf16x8 v; unsigned u[4]; } p;
  p.u[0] = cvtpk((&br[0].x)[c], (&br[1].x)[c]);
  p.u[1] = cvtpk((&br[2].x)[c], (&br[3].x)[c]);
  p.u[2] = cvtpk((&br[4].x)[c], (&br[5].x)[c]);
  p.u[3] = cvtpk((&br[6].x)[c], (&br[7].x)[c]);
  return p.v;
}

// ---------------- router (also records each token's two global slots) -------
__global__ void router_kernel(const float* __restrict__ x, const float* __restrict__ Wr,
                              int* __restrict__ cnt, int* __restrict__ tok,
                              float* __restrict__ prb, int* __restrict__ tsl) {
  int t = (blockIdx.x * blockDim.x + threadIdx.x) >> 6;
  int lane = threadIdx.x & 63;
  if (t >= T_TOK) return;
  const float* xr = x + (size_t)t * DDIM;
  float acc[NEXP];
#pragma unroll
  for (int e = 0; e < NEXP; ++e) acc[e] = 0.f;
#pragma unroll
  for (int i = 0; i < 4; ++i) {
    int d0 = lane * 16 + i * 4;
    float4 xv = *reinterpret_cast<const float4*>(xr + d0);
#pragma unroll
    for (int j = 0; j < 4; ++j) {
      float xd = (&xv.x)[j];
      float4 w0 = *reinterpret_cast<const float4*>(Wr + (size_t)(d0 + j) * NEXP);
      float4 w1 = *reinterpret_cast<const float4*>(Wr + (size_t)(d0 + j) * NEXP + 4);
      acc[0] += xd * w0.x; acc[1] += xd * w0.y; acc[2] += xd * w0.z; acc[3] += xd * w0.w;
      acc[4] += xd * w1.x; acc[5] += xd * w1.y; acc[6] += xd * w1.z; acc[7] += xd * w1.w;
    }
  }
#pragma unroll
  for (int off = 32; off >= 1; off >>= 1)
#pragma unroll
    for (int e = 0; e < NEXP; ++e) acc[e] += __shfl_down(acc[e], off);
  if (lane == 0) {
    float v0 = -1e30f, v1 = -1e30f; int i0 = 0, i1 = 0;
#pragma unroll
    for (int e = 0; e < NEXP; ++e) {
      float v = acc[e];
      if (v > v0)      { v1 = v0; i1 = i0; v0 = v; i0 = e; }
      else if (v > v1) { v1 = v; i1 = e; }
    }
    float e1 = __expf(v1 - v0);
    float p0 = 1.f / (1.f + e1);
    float p1 = e1 * p0;
    int s0 = atomicAdd(&cnt[i0], 1);
    tok[i0 * T_TOK + s0] = t; prb[i0 * T_TOK + s0] = p0;
    int s1 = atomicAdd(&cnt[i1], 1);
    tok[i1 * T_TOK + s1] = t; prb[i1 * T_TOK + s1] = p1;
    tsl[t * 2]     = i0 * T_TOK + s0;
    tsl[t * 2 + 1] = i1 * T_TOK + s1;
  }
}

// ---------------- gather+cvt: xg[off_e + s] = bf16(x[tok[e][s]]) ------------
__global__ void gather_x_kernel(const float* __restrict__ x, const int* __restrict__ cnt,
                                const int* __restrict__ tok, unsigned short* __restrict__ xg) {
  int gs = blockIdx.x * 4 + (threadIdx.x >> 6);   // global slot [0, 4096)
  int lane = threadIdx.x & 63;
  int s = gs, e = 0;
#pragma unroll
  for (int i = 0; i < NEXP - 1; ++i) {
    int c = cnt[i];
    bool go = (e == i) && (s >= c);
    if (go) { s -= c; e = i + 1; }
  }
  int tk = tok[e * T_TOK + s];
  const float* src = x + (size_t)tk * DDIM;
  unsigned short* dst = xg + (size_t)gs * DDIM;
#pragma unroll
  for (int it = 0; it < 4; ++it) {
    float4 v = *reinterpret_cast<const float4*>(src + it * 256 + lane * 4);
    uint2 p;
    p.x = cvtpk(v.x, v.y);
    p.y = cvtpk(v.z, v.w);
    *reinterpret_cast<uint2*>(dst + it * 256 + lane * 4) = p;
  }
}

// ======== fused GEMM1: act = silu(xg@W1) * (xg@W3) [champion, verbatim] =====
__global__ __launch_bounds__(256, 3)
void gemm1ab_kernel(const unsigned short* __restrict__ xg,
                    const float* __restrict__ W1, const float* __restrict__ W3,
                    const int* __restrict__ cnt,
                    unsigned short* __restrict__ act) {
  const int e = blockIdx.z;
  const int cn = cnt[e];
  const int r0 = blockIdx.y * 128;
  if (r0 >= cn) return;
  const int n0 = blockIdx.x * 64;
  int off = 0;
#pragma unroll
  for (int i = 0; i < NEXP; ++i) off += (i < e) ? cnt[i] : 0;

  __shared__ __align__(16) unsigned short sA[128 * 64];      // 16 KB
  __shared__ __align__(16) unsigned short sB1[64 * 64];      // 8 KB
  __shared__ __align__(16) unsigned short sB3[64 * 64];      // 8 KB

  const int tid = threadIdx.x;
  const int lane = tid & 63;
  const int wid = tid >> 6;
  const int wm = wid >> 1, wn = wid & 1;

  const unsigned short* asrc[4];
#pragma unroll
  for (int i = 0; i < 4; ++i) {
    int row = (4 * wid + i) * 8 + (lane >> 3);
    int sl = (lane & 7) ^ (row & 7);
    asrc[i] = xg + (size_t)(off + r0 + row) * DDIM + sl * 8;
  }

  const int lt = tid & 127;
  const int ko = lt >> 4;
  const int nc = (lt & 15) * 4;
  const float* bp = ((tid < 128) ? W1 : W3) + ((size_t)e * DDIM + 8 * ko) * FDIM + n0 + nc;
  unsigned short* wb = (tid < 128) ? sB1 : sB3;
  int woff[4];
#pragma unroll
  for (int c = 0; c < 4; ++c) woff[c] = (nc + c) * 64 + ((ko ^ SBW(nc + c)) * 8);

  float4 br[8];
#define LOADB1(K0)                                                              \
  _Pragma("unroll") for (int r = 0; r < 8; ++r)                                 \
      br[r] = *reinterpret_cast<const float4*>(bp + (size_t)((K0) + r) * FDIM);
#define WRITEB1()                                                               \
  _Pragma("unroll") for (int c = 0; c < 4; ++c)                                 \
      *reinterpret_cast<bf16x8*>(wb + woff[c]) = pack8(br, c);
#define STAGEA1(K0)                                                             \
  _Pragma("unroll") for (int i = 0; i < 4; ++i)                                 \
      gl16(asrc[i] + (K0), &sA[(4 * wid + i) * 512]);

  f32x4 ah[4][2], ag[4][2];
#pragma unroll
  for (int m = 0; m < 4; ++m)
#pragma unroll
    for (int n = 0; n < 2; ++n) { ah[m][n] = (f32x4){0,0,0,0}; ag[m][n] = (f32x4){0,0,0,0}; }

  LOADB1(0);

  for (int k0 = 0; k0 < DDIM; k0 += 64) {
    WRITEB1();
    STAGEA1(k0);
    __syncthreads();
    if (k0 + 64 < DDIM) LOADB1(k0 + 64);
#pragma unroll
    for (int kk = 0; kk < 2; ++kk) {
      int kc8 = kk * 4 + (lane >> 4);
      bf16x8 a[4], b1[2], b3[2];
#pragma unroll
      for (int m = 0; m < 4; ++m) {
        int row = wm * 64 + m * 16 + (lane & 15);
        a[m] = *reinterpret_cast<const bf16x8*>(&sA[row * 64 + ((kc8 ^ (row & 7)) * 8)]);
      }
#pragma unroll
      for (int n = 0; n < 2; ++n) {
        int rowb = wn * 32 + n * 16 + (lane & 15);
        int offb = rowb * 64 + ((kc8 ^ SBW(rowb)) * 8);
        b1[n] = *reinterpret_cast<const bf16x8*>(&sB1[offb]);
        b3[n] = *reinterpret_cast<const bf16x8*>(&sB3[offb]);
      }
#pragma unroll
      for (int m = 0; m < 4; ++m)
#pragma unroll
        for (int n = 0; n < 2; ++n) {
          ah[m][n] = __builtin_amdgcn_mfma_f32_16x16x32_bf16(a[m], b1[n], ah[m][n], 0, 0, 0);
          ag[m][n] = __builtin_amdgcn_mfma_f32_16x16x32_bf16(a[m], b3[n], ag[m][n], 0, 0, 0);
        }
    }
    __syncthreads();
  }
#pragma unroll
  for (int m = 0; m < 4; ++m)
#pragma unroll
    for (int j = 0; j < 4; ++j) {
      int rloc = wm * 64 + m * 16 + (lane >> 4) * 4 + j;
      int s = r0 + rloc;
      if (s < cn) {
        unsigned short* orow = act + (size_t)(off + s) * FDIM + n0 + wn * 32 + (lane & 15);
#pragma unroll
        for (int n = 0; n < 2; ++n) {
          float hv = ah[m][n][j];
          float gv = ag[m][n][j];
          float sg = hv / (1.f + __expf(-hv));
          orow[n * 16] = f2b(sg * gv);
        }
      }
    }
}

// ======== GEMM2p: y[sp] = act @ W2 (split-K=2, plain stores) ========
__global__ __launch_bounds__(256, 3)
void gemm2p_kernel(const unsigned short* __restrict__ act, const float* __restrict__ W2,
                   const int* __restrict__ cnt,
                   float* __restrict__ y0, float* __restrict__ y1) {
  const int e = blockIdx.z >> 1;
  const int sp = blockIdx.z & 1;
  const int cn = cnt[e];
  const int r0 = blockIdx.y * 128;
  if (r0 >= cn) return;
  const int n0 = blockIdx.x * 128;
  const int kbase = sp * (FDIM / 2);
  int off = 0;
#pragma unroll
  for (int i = 0; i < NEXP; ++i) off += (i < e) ? cnt[i] : 0;

  __shared__ __align__(16) unsigned short sA[128 * 64];      // 16 KB
  __shared__ __align__(16) unsigned short sB[128 * 64];      // 16 KB

  const int tid = threadIdx.x;
  const int lane = tid & 63;
  const int wid = tid >> 6;
  const int wm = wid >> 1, wn = wid & 1;

  const unsigned short* asrc[4];
#pragma unroll
  for (int i = 0; i < 4; ++i) {
    int row = (4 * wid + i) * 8 + (lane >> 3);
    int sl = (lane & 7) ^ (row & 7);
    asrc[i] = act + (size_t)(off + r0 + row) * FDIM + kbase + sl * 8;
  }

  const int ko = tid >> 5;          // 0..7
  const int nc = (tid & 31) * 4;    // 0..124
  const float* bp = W2 + ((size_t)e * FDIM + kbase + 8 * ko) * DDIM + n0 + nc;
  int woff[4];
#pragma unroll
  for (int c = 0; c < 4; ++c) woff[c] = (nc + c) * 64 + ((ko ^ SBW(nc + c)) * 8);

  float4 br[8];
#define LOADB2(K0)                                                              \
  _Pragma("unroll") for (int r = 0; r < 8; ++r)                                 \
      br[r] = *reinterpret_cast<const float4*>(bp + (size_t)((K0) + r) * DDIM);
#define WRITEB2()                                                               \
  _Pragma("unroll") for (int c = 0; c < 4; ++c)                                 \
      *reinterpret_cast<bf16x8*>(&sB[woff[c]]) = pack8(br, c);
#define STAGEA2(K0)                                                             \
  _Pragma("unroll") for (int i = 0; i < 4; ++i)                                 \
      gl16(asrc[i] + (K0), &sA[(4 * wid + i) * 512]);

  f32x4 acc[4][4];
#pragma unroll
  for (int m = 0; m < 4; ++m)
#pragma unroll
    for (int n = 0; n < 4; ++n) acc[m][n] = (f32x4){0,0,0,0};

  LOADB2(0);

  for (int k0 = 0; k0 < FDIM / 2; k0 += 64) {
    WRITEB2();
    STAGEA2(k0);
    __syncthreads();
    if (k0 + 64 < FDIM / 2) LOADB2(k0 + 64);
#pragma unroll
    for (int kk = 0; kk < 2; ++kk) {
      int kc8 = kk * 4 + (lane >> 4);
      bf16x8 a[4], b[4];
#pragma unroll
      for (int m = 0; m < 4; ++m) {
        int row = wm * 64 + m * 16 + (lane & 15);
        a[m] = *reinterpret_cast<const bf16x8*>(&sA[row * 64 + ((kc8 ^ (row & 7)) * 8)]);
      }
#pragma unroll
      for (int n = 0; n < 4; ++n) {
        int col = wn * 64 + n * 16 + (lane & 15);
        b[n] = *reinterpret_cast<const bf16x8*>(&sB[col * 64 + ((kc8 ^ SBW(col)) * 8)]);
      }
#pragma unroll
      for (int m = 0; m < 4; ++m)
#pragma unroll
        for (int n = 0; n < 4; ++n)
          acc[m][n] = __builtin_amdgcn_mfma_f32_16x16x32_bf16(a[m], b[n], acc[m][n], 0, 0, 0);
    }
    __syncthreads();
  }
  float* yb = (sp ? y1 : y0);
#pragma unroll
  for (int m = 0; m < 4; ++m)
#pragma unroll
    for (int j = 0; j < 4; ++j) {
      int rloc = wm * 64 + m * 16 + (lane >> 4) * 4 + j;
      int s = r0 + rloc;
      if (s < cn) {
        float* orow = yb + (size_t)(off + s) * DDIM + n0 + wn * 64 + (lane & 15);
#pragma unroll
        for (int n = 0; n < 4; ++n) orow[n * 16] = acc[m][n][j];
      }
    }
}

// ---------------- combine: out[t] = p0*(y0+y1)[g0] + p1*(y0+y1)[g1] ---------
__global__ void combine_kernel(const float* __restrict__ y0, const float* __restrict__ y1,
                               const int* __restrict__ cnt, const int* __restrict__ tsl,
                               const float* __restrict__ prb, float* __restrict__ out) {
  const int t = blockIdx.x;
  int pre[NEXP];
  pre[0] = 0;
#pragma unroll
  for (int i = 1; i < NEXP; ++i) pre[i] = pre[i - 1] + cnt[i - 1];
  int a = tsl[t * 2], b = tsl[t * 2 + 1];
  int ea = a >> 11, sa = a & (T_TOK - 1);
  int eb = b >> 11, sb = b & (T_TOK - 1);
  size_t ga = (size_t)(pre[ea] + sa) * DDIM;
  size_t gb = (size_t)(pre[eb] + sb) * DDIM;
  float pa = prb[a], pb = prb[b];
  int c = threadIdx.x * 4;
  float4 a0 = *reinterpret_cast<const float4*>(y0 + ga + c);
  float4 a1 = *reinterpret_cast<const float4*>(y1 + ga + c);
  float4 b0 = *reinterpret_cast<const float4*>(y0 + gb + c);
  float4 b1 = *reinterpret_cast<const float4*>(y1 + gb + c);
  float4 o;
  o.x = pa * (a0.x + a1.x) + pb * (b0.x + b1.x);
  o.y = pa * (a0.y + a1.y) + pb * (b0.y + b1.y);
  o.z = pa * (a0.z + a1.z) + pb * (b0.z + b1.z);
  o.w = pa * (a0.w + a1.w) + pb * (b0.w + b1.w);
  *reinterpret_cast<float4*>(out + (size_t)t * DDIM + c) = o;
}

// ============================================================================
extern "C" void kernel_launch(void* const* d_in, const int* in_sizes, int n_in,
                              void* d_out, int out_size, void* d_ws, size_t ws_size,
                              hipStream_t stream) {
  const float* x  = (const float*)d_in[0];
  const float* Wr = (const float*)d_in[1];
  const float* W1 = (const float*)d_in[2];
  const float* W2 = (const float*)d_in[3];
  const float* W3 = (const float*)d_in[4];
  float* out = (float*)d_out;

  char* ws = (char*)d_ws;
  int*   cnt = (int*)ws;                      // 32 B
  int*   tok = (int*)(ws + 1024);             // 64 KB
  float* prb = (float*)(ws + 1024 + 65536);   // 64 KB
  int*   tsl = (int*)(ws + 1024 + 2 * 65536); // 16 KB
  unsigned short* xg  = (unsigned short*)(ws + 256 * 1024);   // ROWS x DDIM bf16
  unsigned short* act = xg + (size_t)ROWS * DDIM;             // ROWS x FDIM bf16
  float* y0 = (float*)(act + (size_t)ROWS * FDIM);            // ROWS x DDIM f32
  float* y1 = y0 + (size_t)ROWS * DDIM;                       // ROWS x DDIM f32

  hipMemsetAsync(cnt, 0, NEXP * sizeof(int), stream);

  router_kernel<<<T_TOK / 4, 256, 0, stream>>>(x, Wr, cnt, tok, prb, tsl);
  gather_x_kernel<<<(2 * T_TOK) / 4, 256, 0, stream>>>(x, cnt, tok, xg);
  gemm1ab_kernel<<<dim3(FDIM / 64, 16, NEXP), 256, 0, stream>>>(xg, W1, W3, cnt, act);
  gemm2p_kernel<<<dim3(DDIM / 128, 16, NEXP * 2), 256, 0, stream>>>(act, W2, cnt, y0, y1);
  combine_kernel<<<T_TOK, 256, 0, stream>>>(y0, y1, cnt, tsl, prb, out);
}

// Round 21
// 282.653 us; speedup vs baseline: 1.4734x; 1.0266x over previous
//
#include <hip/hip_runtime.h>
#include <hip/hip_bf16.h>

#define T_TOK 2048
#define DDIM  1024
#define NEXP  8
#define FDIM  4096
#define ROWS  (4096 + 256)

typedef __attribute__((ext_vector_type(8))) short bf16x8;
typedef __attribute__((ext_vector_type(4))) float f32x4;

#define SBW(n) ((((n) >> 3) ^ (n)) & 7)

__device__ __forceinline__ unsigned short f2b(float f) {
  union { float f; unsigned u; } v; v.f = f;
  unsigned r = v.u + 0x7FFF + ((v.u >> 16) & 1);  // RNE
  return (unsigned short)(r >> 16);
}
__device__ __forceinline__ float b2f(unsigned short s) {
  union { unsigned u; float f; } v; v.u = ((unsigned)s) << 16;
  return v.f;
}
__device__ __forceinline__ unsigned cvtpk(float lo, float hi) {
  unsigned r;
  asm("v_cvt_pk_bf16_f32 %0, %1, %2" : "=v"(r) : "v"(lo), "v"(hi));
  return r;
}
__device__ __forceinline__ void gl16(const unsigned short* g, unsigned short* l) {
  __builtin_amdgcn_global_load_lds(
      (const __attribute__((address_space(1))) unsigned int*)(const void*)g,
      (__attribute__((address_space(3))) unsigned int*)(void*)l, 16, 0, 0);
}
__device__ __forceinline__ bf16x8 pack8(const float4* br, int c) {
  union { bf16x8 v; unsigned u[4]; } p;
  p.u[0] = cvtpk((&br[0].x)[c], (&br[1].x)[c]);
  p.u[1] = cvtpk((&br[2].x)[c], (&br[3].x)[c]);
  p.u[2] = cvtpk((&br[4].x)[c], (&br[5].x)[c]);
  p.u[3] = cvtpk((&br[6].x)[c], (&br[7].x)[c]);
  return p.v;
}

// ---------------- router (also records each token's two global slots) -------
__global__ void router_kernel(const float* __restrict__ x, const float* __restrict__ Wr,
                              int* __restrict__ cnt, int* __restrict__ tok,
                              float* __restrict__ prb, int* __restrict__ tsl) {
  int t = (blockIdx.x * blockDim.x + threadIdx.x) >> 6;
  int lane = threadIdx.x & 63;
  if (t >= T_TOK) return;
  const float* xr = x + (size_t)t * DDIM;
  float acc[NEXP];
#pragma unroll
  for (int e = 0; e < NEXP; ++e) acc[e] = 0.f;
#pragma unroll
  for (int i = 0; i < 4; ++i) {
    int d0 = lane * 16 + i * 4;
    float4 xv = *reinterpret_cast<const float4*>(xr + d0);
#pragma unroll
    for (int j = 0; j < 4; ++j) {
      float xd = (&xv.x)[j];
      float4 w0 = *reinterpret_cast<const float4*>(Wr + (size_t)(d0 + j) * NEXP);
      float4 w1 = *reinterpret_cast<const float4*>(Wr + (size_t)(d0 + j) * NEXP + 4);
      acc[0] += xd * w0.x; acc[1] += xd * w0.y; acc[2] += xd * w0.z; acc[3] += xd * w0.w;
      acc[4] += xd * w1.x; acc[5] += xd * w1.y; acc[6] += xd * w1.z; acc[7] += xd * w1.w;
    }
  }
#pragma unroll
  for (int off = 32; off >= 1; off >>= 1)
#pragma unroll
    for (int e = 0; e < NEXP; ++e) acc[e] += __shfl_down(acc[e], off);
  if (lane == 0) {
    float v0 = -1e30f, v1 = -1e30f; int i0 = 0, i1 = 0;
#pragma unroll
    for (int e = 0; e < NEXP; ++e) {
      float v = acc[e];
      if (v > v0)      { v1 = v0; i1 = i0; v0 = v; i0 = e; }
      else if (v > v1) { v1 = v; i1 = e; }
    }
    float e1 = __expf(v1 - v0);
    float p0 = 1.f / (1.f + e1);
    float p1 = e1 * p0;
    int s0 = atomicAdd(&cnt[i0], 1);
    tok[i0 * T_TOK + s0] = t; prb[i0 * T_TOK + s0] = p0;
    int s1 = atomicAdd(&cnt[i1], 1);
    tok[i1 * T_TOK + s1] = t; prb[i1 * T_TOK + s1] = p1;
    tsl[t * 2]     = i0 * T_TOK + s0;
    tsl[t * 2 + 1] = i1 * T_TOK + s1;
  }
}

// ---------------- gather+cvt: xg[off_e + s] = bf16(x[tok[e][s]]) ------------
__global__ void gather_x_kernel(const float* __restrict__ x, const int* __restrict__ cnt,
                                const int* __restrict__ tok, unsigned short* __restrict__ xg) {
  int gs = blockIdx.x * 4 + (threadIdx.x >> 6);   // global slot [0, 4096)
  int lane = threadIdx.x & 63;
  int s = gs, e = 0;
#pragma unroll
  for (int i = 0; i < NEXP - 1; ++i) {
    int c = cnt[i];
    bool go = (e == i) && (s >= c);
    if (go) { s -= c; e = i + 1; }
  }
  int tk = tok[e * T_TOK + s];
  const float* src = x + (size_t)tk * DDIM;
  unsigned short* dst = xg + (size_t)gs * DDIM;
#pragma unroll
  for (int it = 0; it < 4; ++it) {
    float4 v = *reinterpret_cast<const float4*>(src + it * 256 + lane * 4);
    uint2 p;
    p.x = cvtpk(v.x, v.y);
    p.y = cvtpk(v.z, v.w);
    *reinterpret_cast<uint2*>(dst + it * 256 + lane * 4) = p;
  }
}

// ======== fused GEMM1: act = silu(xg@W1) * (xg@W3) [champion, verbatim] =====
__global__ __launch_bounds__(256, 3)
void gemm1ab_kernel(const unsigned short* __restrict__ xg,
                    const float* __restrict__ W1, const float* __restrict__ W3,
                    const int* __restrict__ cnt,
                    unsigned short* __restrict__ act) {
  const int e = blockIdx.z;
  const int cn = cnt[e];
  const int r0 = blockIdx.y * 128;
  if (r0 >= cn) return;
  const int n0 = blockIdx.x * 64;
  int off = 0;
#pragma unroll
  for (int i = 0; i < NEXP; ++i) off += (i < e) ? cnt[i] : 0;

  __shared__ __align__(16) unsigned short sA[128 * 64];      // 16 KB
  __shared__ __align__(16) unsigned short sB1[64 * 64];      // 8 KB
  __shared__ __align__(16) unsigned short sB3[64 * 64];      // 8 KB

  const int tid = threadIdx.x;
  const int lane = tid & 63;
  const int wid = tid >> 6;
  const int wm = wid >> 1, wn = wid & 1;

  const unsigned short* asrc[4];
#pragma unroll
  for (int i = 0; i < 4; ++i) {
    int row = (4 * wid + i) * 8 + (lane >> 3);
    int sl = (lane & 7) ^ (row & 7);
    asrc[i] = xg + (size_t)(off + r0 + row) * DDIM + sl * 8;
  }

  const int lt = tid & 127;
  const int ko = lt >> 4;
  const int nc = (lt & 15) * 4;
  const float* bp = ((tid < 128) ? W1 : W3) + ((size_t)e * DDIM + 8 * ko) * FDIM + n0 + nc;
  unsigned short* wb = (tid < 128) ? sB1 : sB3;
  int woff[4];
#pragma unroll
  for (int c = 0; c < 4; ++c) woff[c] = (nc + c) * 64 + ((ko ^ SBW(nc + c)) * 8);

  float4 br[8];
#define LOADB1(K0)                                                              \
  _Pragma("unroll") for (int r = 0; r < 8; ++r)                                 \
      br[r] = *reinterpret_cast<const float4*>(bp + (size_t)((K0) + r) * FDIM);
#define WRITEB1()                                                               \
  _Pragma("unroll") for (int c = 0; c < 4; ++c)                                 \
      *reinterpret_cast<bf16x8*>(wb + woff[c]) = pack8(br, c);
#define STAGEA1(K0)                                                             \
  _Pragma("unroll") for (int i = 0; i < 4; ++i)                                 \
      gl16(asrc[i] + (K0), &sA[(4 * wid + i) * 512]);

  f32x4 ah[4][2], ag[4][2];
#pragma unroll
  for (int m = 0; m < 4; ++m)
#pragma unroll
    for (int n = 0; n < 2; ++n) { ah[m][n] = (f32x4){0,0,0,0}; ag[m][n] = (f32x4){0,0,0,0}; }

  LOADB1(0);

  for (int k0 = 0; k0 < DDIM; k0 += 64) {
    WRITEB1();
    STAGEA1(k0);
    __syncthreads();
    if (k0 + 64 < DDIM) LOADB1(k0 + 64);
#pragma unroll
    for (int kk = 0; kk < 2; ++kk) {
      int kc8 = kk * 4 + (lane >> 4);
      bf16x8 a[4], b1[2], b3[2];
#pragma unroll
      for (int m = 0; m < 4; ++m) {
        int row = wm * 64 + m * 16 + (lane & 15);
        a[m] = *reinterpret_cast<const bf16x8*>(&sA[row * 64 + ((kc8 ^ (row & 7)) * 8)]);
      }
#pragma unroll
      for (int n = 0; n < 2; ++n) {
        int rowb = wn * 32 + n * 16 + (lane & 15);
        int offb = rowb * 64 + ((kc8 ^ SBW(rowb)) * 8);
        b1[n] = *reinterpret_cast<const bf16x8*>(&sB1[offb]);
        b3[n] = *reinterpret_cast<const bf16x8*>(&sB3[offb]);
      }
#pragma unroll
      for (int m = 0; m < 4; ++m)
#pragma unroll
        for (int n = 0; n < 2; ++n) {
          ah[m][n] = __builtin_amdgcn_mfma_f32_16x16x32_bf16(a[m], b1[n], ah[m][n], 0, 0, 0);
          ag[m][n] = __builtin_amdgcn_mfma_f32_16x16x32_bf16(a[m], b3[n], ag[m][n], 0, 0, 0);
        }
    }
    __syncthreads();
  }
#pragma unroll
  for (int m = 0; m < 4; ++m)
#pragma unroll
    for (int j = 0; j < 4; ++j) {
      int rloc = wm * 64 + m * 16 + (lane >> 4) * 4 + j;
      int s = r0 + rloc;
      if (s < cn) {
        unsigned short* orow = act + (size_t)(off + s) * FDIM + n0 + wn * 32 + (lane & 15);
#pragma unroll
        for (int n = 0; n < 2; ++n) {
          float hv = ah[m][n][j];
          float gv = ag[m][n][j];
          float sg = hv / (1.f + __expf(-hv));
          orow[n * 16] = f2b(sg * gv);
        }
      }
    }
}

// ======== GEMM2p: y[sp] = act @ W2 (split-K=4, bf16 partial stores) ========
__global__ __launch_bounds__(256, 3)
void gemm2p_kernel(const unsigned short* __restrict__ act, const float* __restrict__ W2,
                   const int* __restrict__ cnt,
                   unsigned short* __restrict__ y) {
  const int e = blockIdx.z >> 2;
  const int sp = blockIdx.z & 3;
  const int cn = cnt[e];
  const int r0 = blockIdx.y * 128;
  if (r0 >= cn) return;
  const int n0 = blockIdx.x * 128;
  const int kbase = sp * (FDIM / 4);
  int off = 0;
#pragma unroll
  for (int i = 0; i < NEXP; ++i) off += (i < e) ? cnt[i] : 0;

  __shared__ __align__(16) unsigned short sA[128 * 64];      // 16 KB
  __shared__ __align__(16) unsigned short sB[128 * 64];      // 16 KB

  const int tid = threadIdx.x;
  const int lane = tid & 63;
  const int wid = tid >> 6;
  const int wm = wid >> 1, wn = wid & 1;

  const unsigned short* asrc[4];
#pragma unroll
  for (int i = 0; i < 4; ++i) {
    int row = (4 * wid + i) * 8 + (lane >> 3);
    int sl = (lane & 7) ^ (row & 7);
    asrc[i] = act + (size_t)(off + r0 + row) * FDIM + kbase + sl * 8;
  }

  const int ko = tid >> 5;          // 0..7
  const int nc = (tid & 31) * 4;    // 0..124
  const float* bp = W2 + ((size_t)e * FDIM + kbase + 8 * ko) * DDIM + n0 + nc;
  int woff[4];
#pragma unroll
  for (int c = 0; c < 4; ++c) woff[c] = (nc + c) * 64 + ((ko ^ SBW(nc + c)) * 8);

  float4 br[8];
#define LOADB2(K0)                                                              \
  _Pragma("unroll") for (int r = 0; r < 8; ++r)                                 \
      br[r] = *reinterpret_cast<const float4*>(bp + (size_t)((K0) + r) * DDIM);
#define WRITEB2()                                                               \
  _Pragma("unroll") for (int c = 0; c < 4; ++c)                                 \
      *reinterpret_cast<bf16x8*>(&sB[woff[c]]) = pack8(br, c);
#define STAGEA2(K0)                                                             \
  _Pragma("unroll") for (int i = 0; i < 4; ++i)                                 \
      gl16(asrc[i] + (K0), &sA[(4 * wid + i) * 512]);

  f32x4 acc[4][4];
#pragma unroll
  for (int m = 0; m < 4; ++m)
#pragma unroll
    for (int n = 0; n < 4; ++n) acc[m][n] = (f32x4){0,0,0,0};

  LOADB2(0);

  for (int k0 = 0; k0 < FDIM / 4; k0 += 64) {
    WRITEB2();
    STAGEA2(k0);
    __syncthreads();
    if (k0 + 64 < FDIM / 4) LOADB2(k0 + 64);
#pragma unroll
    for (int kk = 0; kk < 2; ++kk) {
      int kc8 = kk * 4 + (lane >> 4);
      bf16x8 a[4], b[4];
#pragma unroll
      for (int m = 0; m < 4; ++m) {
        int row = wm * 64 + m * 16 + (lane & 15);
        a[m] = *reinterpret_cast<const bf16x8*>(&sA[row * 64 + ((kc8 ^ (row & 7)) * 8)]);
      }
#pragma unroll
      for (int n = 0; n < 4; ++n) {
        int col = wn * 64 + n * 16 + (lane & 15);
        b[n] = *reinterpret_cast<const bf16x8*>(&sB[col * 64 + ((kc8 ^ SBW(col)) * 8)]);
      }
#pragma unroll
      for (int m = 0; m < 4; ++m)
#pragma unroll
        for (int n = 0; n < 4; ++n)
          acc[m][n] = __builtin_amdgcn_mfma_f32_16x16x32_bf16(a[m], b[n], acc[m][n], 0, 0, 0);
    }
    __syncthreads();
  }
  unsigned short* yb = y + (size_t)sp * ROWS * DDIM;
#pragma unroll
  for (int m = 0; m < 4; ++m)
#pragma unroll
    for (int j = 0; j < 4; ++j) {
      int rloc = wm * 64 + m * 16 + (lane >> 4) * 4 + j;
      int s = r0 + rloc;
      if (s < cn) {
        unsigned short* orow = yb + (size_t)(off + s) * DDIM + n0 + wn * 64 + (lane & 15);
#pragma unroll
        for (int n = 0; n < 4; ++n) orow[n * 16] = f2b(acc[m][n][j]);
      }
    }
}

// ------- combine: out[t] = p0*sum4(y[.][g0]) + p1*sum4(y[.][g1]) ------------
__global__ void combine_kernel(const unsigned short* __restrict__ y,
                               const int* __restrict__ cnt, const int* __restrict__ tsl,
                               const float* __restrict__ prb, float* __restrict__ out) {
  const int t = blockIdx.x;
  int pre[NEXP];
  pre[0] = 0;
#pragma unroll
  for (int i = 1; i < NEXP; ++i) pre[i] = pre[i - 1] + cnt[i - 1];
  int a = tsl[t * 2], b = tsl[t * 2 + 1];
  int ea = a >> 11, sa = a & (T_TOK - 1);
  int eb = b >> 11, sb = b & (T_TOK - 1);
  size_t ga = (size_t)(pre[ea] + sa) * DDIM;
  size_t gb = (size_t)(pre[eb] + sb) * DDIM;
  float pa = prb[a], pb = prb[b];
  int c = threadIdx.x * 4;
  float sA0 = 0.f, sA1 = 0.f, sA2 = 0.f, sA3 = 0.f;
  float sB0 = 0.f, sB1 = 0.f, sB2 = 0.f, sB3 = 0.f;
#pragma unroll
  for (int sp = 0; sp < 4; ++sp) {
    const unsigned short* yb = y + (size_t)sp * ROWS * DDIM;
    uint2 va = *reinterpret_cast<const uint2*>(yb + ga + c);
    uint2 vb = *reinterpret_cast<const uint2*>(yb + gb + c);
    sA0 += b2f((unsigned short)(va.x & 0xFFFF));
    sA1 += b2f((unsigned short)(va.x >> 16));
    sA2 += b2f((unsigned short)(va.y & 0xFFFF));
    sA3 += b2f((unsigned short)(va.y >> 16));
    sB0 += b2f((unsigned short)(vb.x & 0xFFFF));
    sB1 += b2f((unsigned short)(vb.x >> 16));
    sB2 += b2f((unsigned short)(vb.y & 0xFFFF));
    sB3 += b2f((unsigned short)(vb.y >> 16));
  }
  float4 o;
  o.x = pa * sA0 + pb * sB0;
  o.y = pa * sA1 + pb * sB1;
  o.z = pa * sA2 + pb * sB2;
  o.w = pa * sA3 + pb * sB3;
  *reinterpret_cast<float4*>(out + (size_t)t * DDIM + c) = o;
}

// ============================================================================
extern "C" void kernel_launch(void* const* d_in, const int* in_sizes, int n_in,
                              void* d_out, int out_size, void* d_ws, size_t ws_size,
                              hipStream_t stream) {
  const float* x  = (const float*)d_in[0];
  const float* Wr = (const float*)d_in[1];
  const float* W1 = (const float*)d_in[2];
  const float* W2 = (const float*)d_in[3];
  const float* W3 = (const float*)d_in[4];
  float* out = (float*)d_out;

  char* ws = (char*)d_ws;
  int*   cnt = (int*)ws;                      // 32 B
  int*   tok = (int*)(ws + 1024);             // 64 KB
  float* prb = (float*)(ws + 1024 + 65536);   // 64 KB
  int*   tsl = (int*)(ws + 1024 + 2 * 65536); // 16 KB
  unsigned short* xg  = (unsigned short*)(ws + 256 * 1024);   // ROWS x DDIM bf16
  unsigned short* act = xg + (size_t)ROWS * DDIM;             // ROWS x FDIM bf16
  unsigned short* y   = act + (size_t)ROWS * FDIM;            // 4 x ROWS x DDIM bf16

  hipMemsetAsync(cnt, 0, NEXP * sizeof(int), stream);

  router_kernel<<<T_TOK / 4, 256, 0, stream>>>(x, Wr, cnt, tok, prb, tsl);
  gather_x_kernel<<<(2 * T_TOK) / 4, 256, 0, stream>>>(x, cnt, tok, xg);
  gemm1ab_kernel<<<dim3(FDIM / 64, 16, NEXP), 256, 0, stream>>>(xg, W1, W3, cnt, act);
  gemm2p_kernel<<<dim3(DDIM / 128, 16, NEXP * 4), 256, 0, stream>>>(act, W2, cnt, y);
  combine_kernel<<<T_TOK, 256, 0, stream>>>(y, cnt, tsl, prb, out);
}

// Round 22
// 281.079 us; speedup vs baseline: 1.4816x; 1.0056x over previous
//
#include <hip/hip_runtime.h>
#include <hip/hip_bf16.h>

#define T_TOK 2048
#define DDIM  1024
#define NEXP  8
#define FDIM  4096
#define ROWS  (4096 + 256)

typedef __attribute__((ext_vector_type(8))) short bf16x8;
typedef __attribute__((ext_vector_type(4))) float f32x4;

#define SBW(n) ((((n) >> 3) ^ (n)) & 7)

__device__ __forceinline__ unsigned short f2b(float f) {
  union { float f; unsigned u; } v; v.f = f;
  unsigned r = v.u + 0x7FFF + ((v.u >> 16) & 1);  // RNE
  return (unsigned short)(r >> 16);
}
__device__ __forceinline__ float b2f(unsigned short s) {
  union { unsigned u; float f; } v; v.u = ((unsigned)s) << 16;
  return v.f;
}
__device__ __forceinline__ unsigned cvtpk(float lo, float hi) {
  unsigned r;
  asm("v_cvt_pk_bf16_f32 %0, %1, %2" : "=v"(r) : "v"(lo), "v"(hi));
  return r;
}
__device__ __forceinline__ void gl16(const unsigned short* g, unsigned short* l) {
  __builtin_amdgcn_global_load_lds(
      (const __attribute__((address_space(1))) unsigned int*)(const void*)g,
      (__attribute__((address_space(3))) unsigned int*)(void*)l, 16, 0, 0);
}
__device__ __forceinline__ bf16x8 pack8(const float4* br, int c) {
  union { bf16x8 v; unsigned u[4]; } p;
  p.u[0] = cvtpk((&br[0].x)[c], (&br[1].x)[c]);
  p.u[1] = cvtpk((&br[2].x)[c], (&br[3].x)[c]);
  p.u[2] = cvtpk((&br[4].x)[c], (&br[5].x)[c]);
  p.u[3] = cvtpk((&br[6].x)[c], (&br[7].x)[c]);
  return p.v;
}

// ---------------- router (also records each token's two global slots) -------
__global__ void router_kernel(const float* __restrict__ x, const float* __restrict__ Wr,
                              int* __restrict__ cnt, int* __restrict__ tok,
                              float* __restrict__ prb, int* __restrict__ tsl) {
  int t = (blockIdx.x * blockDim.x + threadIdx.x) >> 6;
  int lane = threadIdx.x & 63;
  if (t >= T_TOK) return;
  const float* xr = x + (size_t)t * DDIM;
  float acc[NEXP];
#pragma unroll
  for (int e = 0; e < NEXP; ++e) acc[e] = 0.f;
#pragma unroll
  for (int i = 0; i < 4; ++i) {
    int d0 = lane * 16 + i * 4;
    float4 xv = *reinterpret_cast<const float4*>(xr + d0);
#pragma unroll
    for (int j = 0; j < 4; ++j) {
      float xd = (&xv.x)[j];
      float4 w0 = *reinterpret_cast<const float4*>(Wr + (size_t)(d0 + j) * NEXP);
      float4 w1 = *reinterpret_cast<const float4*>(Wr + (size_t)(d0 + j) * NEXP + 4);
      acc[0] += xd * w0.x; acc[1] += xd * w0.y; acc[2] += xd * w0.z; acc[3] += xd * w0.w;
      acc[4] += xd * w1.x; acc[5] += xd * w1.y; acc[6] += xd * w1.z; acc[7] += xd * w1.w;
    }
  }
#pragma unroll
  for (int off = 32; off >= 1; off >>= 1)
#pragma unroll
    for (int e = 0; e < NEXP; ++e) acc[e] += __shfl_down(acc[e], off);
  if (lane == 0) {
    float v0 = -1e30f, v1 = -1e30f; int i0 = 0, i1 = 0;
#pragma unroll
    for (int e = 0; e < NEXP; ++e) {
      float v = acc[e];
      if (v > v0)      { v1 = v0; i1 = i0; v0 = v; i0 = e; }
      else if (v > v1) { v1 = v; i1 = e; }
    }
    float e1 = __expf(v1 - v0);
    float p0 = 1.f / (1.f + e1);
    float p1 = e1 * p0;
    int s0 = atomicAdd(&cnt[i0], 1);
    tok[i0 * T_TOK + s0] = t; prb[i0 * T_TOK + s0] = p0;
    int s1 = atomicAdd(&cnt[i1], 1);
    tok[i1 * T_TOK + s1] = t; prb[i1 * T_TOK + s1] = p1;
    tsl[t * 2]     = i0 * T_TOK + s0;
    tsl[t * 2 + 1] = i1 * T_TOK + s1;
  }
}

// ---------------- gather+cvt: xg[off_e + s] = bf16(x[tok[e][s]]) ------------
__global__ void gather_x_kernel(const float* __restrict__ x, const int* __restrict__ cnt,
                                const int* __restrict__ tok, unsigned short* __restrict__ xg) {
  int gs = blockIdx.x * 4 + (threadIdx.x >> 6);   // global slot [0, 4096)
  int lane = threadIdx.x & 63;
  int s = gs, e = 0;
#pragma unroll
  for (int i = 0; i < NEXP - 1; ++i) {
    int c = cnt[i];
    bool go = (e == i) && (s >= c);
    if (go) { s -= c; e = i + 1; }
  }
  int tk = tok[e * T_TOK + s];
  const float* src = x + (size_t)tk * DDIM;
  unsigned short* dst = xg + (size_t)gs * DDIM;
#pragma unroll
  for (int it = 0; it < 4; ++it) {
    float4 v = *reinterpret_cast<const float4*>(src + it * 256 + lane * 4);
    uint2 p;
    p.x = cvtpk(v.x, v.y);
    p.y = cvtpk(v.z, v.w);
    *reinterpret_cast<uint2*>(dst + it * 256 + lane * 4) = p;
  }
}

// ======== fused GEMM1: act = silu(xg@W1) * (xg@W3) [champion, verbatim] =====
__global__ __launch_bounds__(256, 3)
void gemm1ab_kernel(const unsigned short* __restrict__ xg,
                    const float* __restrict__ W1, const float* __restrict__ W3,
                    const int* __restrict__ cnt,
                    unsigned short* __restrict__ act) {
  const int e = blockIdx.z;
  const int cn = cnt[e];
  const int r0 = blockIdx.y * 128;
  if (r0 >= cn) return;
  const int n0 = blockIdx.x * 64;
  int off = 0;
#pragma unroll
  for (int i = 0; i < NEXP; ++i) off += (i < e) ? cnt[i] : 0;

  __shared__ __align__(16) unsigned short sA[128 * 64];      // 16 KB
  __shared__ __align__(16) unsigned short sB1[64 * 64];      // 8 KB
  __shared__ __align__(16) unsigned short sB3[64 * 64];      // 8 KB

  const int tid = threadIdx.x;
  const int lane = tid & 63;
  const int wid = tid >> 6;
  const int wm = wid >> 1, wn = wid & 1;

  const unsigned short* asrc[4];
#pragma unroll
  for (int i = 0; i < 4; ++i) {
    int row = (4 * wid + i) * 8 + (lane >> 3);
    int sl = (lane & 7) ^ (row & 7);
    asrc[i] = xg + (size_t)(off + r0 + row) * DDIM + sl * 8;
  }

  const int lt = tid & 127;
  const int ko = lt >> 4;
  const int nc = (lt & 15) * 4;
  const float* bp = ((tid < 128) ? W1 : W3) + ((size_t)e * DDIM + 8 * ko) * FDIM + n0 + nc;
  unsigned short* wb = (tid < 128) ? sB1 : sB3;
  int woff[4];
#pragma unroll
  for (int c = 0; c < 4; ++c) woff[c] = (nc + c) * 64 + ((ko ^ SBW(nc + c)) * 8);

  float4 br[8];
#define LOADB1(K0)                                                              \
  _Pragma("unroll") for (int r = 0; r < 8; ++r)                                 \
      br[r] = *reinterpret_cast<const float4*>(bp + (size_t)((K0) + r) * FDIM);
#define WRITEB1()                                                               \
  _Pragma("unroll") for (int c = 0; c < 4; ++c)                                 \
      *reinterpret_cast<bf16x8*>(wb + woff[c]) = pack8(br, c);
#define STAGEA1(K0)                                                             \
  _Pragma("unroll") for (int i = 0; i < 4; ++i)                                 \
      gl16(asrc[i] + (K0), &sA[(4 * wid + i) * 512]);

  f32x4 ah[4][2], ag[4][2];
#pragma unroll
  for (int m = 0; m < 4; ++m)
#pragma unroll
    for (int n = 0; n < 2; ++n) { ah[m][n] = (f32x4){0,0,0,0}; ag[m][n] = (f32x4){0,0,0,0}; }

  LOADB1(0);

  for (int k0 = 0; k0 < DDIM; k0 += 64) {
    WRITEB1();
    STAGEA1(k0);
    __syncthreads();
    if (k0 + 64 < DDIM) LOADB1(k0 + 64);
#pragma unroll
    for (int kk = 0; kk < 2; ++kk) {
      int kc8 = kk * 4 + (lane >> 4);
      bf16x8 a[4], b1[2], b3[2];
#pragma unroll
      for (int m = 0; m < 4; ++m) {
        int row = wm * 64 + m * 16 + (lane & 15);
        a[m] = *reinterpret_cast<const bf16x8*>(&sA[row * 64 + ((kc8 ^ (row & 7)) * 8)]);
      }
#pragma unroll
      for (int n = 0; n < 2; ++n) {
        int rowb = wn * 32 + n * 16 + (lane & 15);
        int offb = rowb * 64 + ((kc8 ^ SBW(rowb)) * 8);
        b1[n] = *reinterpret_cast<const bf16x8*>(&sB1[offb]);
        b3[n] = *reinterpret_cast<const bf16x8*>(&sB3[offb]);
      }
#pragma unroll
      for (int m = 0; m < 4; ++m)
#pragma unroll
        for (int n = 0; n < 2; ++n) {
          ah[m][n] = __builtin_amdgcn_mfma_f32_16x16x32_bf16(a[m], b1[n], ah[m][n], 0, 0, 0);
          ag[m][n] = __builtin_amdgcn_mfma_f32_16x16x32_bf16(a[m], b3[n], ag[m][n], 0, 0, 0);
        }
    }
    __syncthreads();
  }
#pragma unroll
  for (int m = 0; m < 4; ++m)
#pragma unroll
    for (int j = 0; j < 4; ++j) {
      int rloc = wm * 64 + m * 16 + (lane >> 4) * 4 + j;
      int s = r0 + rloc;
      if (s < cn) {
        unsigned short* orow = act + (size_t)(off + s) * FDIM + n0 + wn * 32 + (lane & 15);
#pragma unroll
        for (int n = 0; n < 2; ++n) {
          float hv = ah[m][n][j];
          float gv = ag[m][n][j];
          float sg = hv / (1.f + __expf(-hv));
          orow[n * 16] = f2b(sg * gv);
        }
      }
    }
}

// ======== GEMM2p: y[sp] = act @ W2 (split-K=4, bf16 partial stores) ========
__global__ __launch_bounds__(256, 3)
void gemm2p_kernel(const unsigned short* __restrict__ act, const float* __restrict__ W2,
                   const int* __restrict__ cnt,
                   unsigned short* __restrict__ y) {
  const int e = blockIdx.z >> 2;
  const int sp = blockIdx.z & 3;
  const int cn = cnt[e];
  const int r0 = blockIdx.y * 128;
  if (r0 >= cn) return;
  const int n0 = blockIdx.x * 128;
  const int kbase = sp * (FDIM / 4);
  int off = 0;
#pragma unroll
  for (int i = 0; i < NEXP; ++i) off += (i < e) ? cnt[i] : 0;

  __shared__ __align__(16) unsigned short sA[128 * 64];      // 16 KB
  __shared__ __align__(16) unsigned short sB[128 * 64];      // 16 KB

  const int tid = threadIdx.x;
  const int lane = tid & 63;
  const int wid = tid >> 6;
  const int wm = wid >> 1, wn = wid & 1;

  const unsigned short* asrc[4];
#pragma unroll
  for (int i = 0; i < 4; ++i) {
    int row = (4 * wid + i) * 8 + (lane >> 3);
    int sl = (lane & 7) ^ (row & 7);
    asrc[i] = act + (size_t)(off + r0 + row) * FDIM + kbase + sl * 8;
  }

  const int ko = tid >> 5;          // 0..7
  const int nc = (tid & 31) * 4;    // 0..124
  const float* bp = W2 + ((size_t)e * FDIM + kbase + 8 * ko) * DDIM + n0 + nc;
  int woff[4];
#pragma unroll
  for (int c = 0; c < 4; ++c) woff[c] = (nc + c) * 64 + ((ko ^ SBW(nc + c)) * 8);

  float4 br[8];
#define LOADB2(K0)                                                              \
  _Pragma("unroll") for (int r = 0; r < 8; ++r)                                 \
      br[r] = *reinterpret_cast<const float4*>(bp + (size_t)((K0) + r) * DDIM);
#define WRITEB2()                                                               \
  _Pragma("unroll") for (int c = 0; c < 4; ++c)                                 \
      *reinterpret_cast<bf16x8*>(&sB[woff[c]]) = pack8(br, c);
#define STAGEA2(K0)                                                             \
  _Pragma("unroll") for (int i = 0; i < 4; ++i)                                 \
      gl16(asrc[i] + (K0), &sA[(4 * wid + i) * 512]);

  f32x4 acc[4][4];
#pragma unroll
  for (int m = 0; m < 4; ++m)
#pragma unroll
    for (int n = 0; n < 4; ++n) acc[m][n] = (f32x4){0,0,0,0};

  LOADB2(0);

  for (int k0 = 0; k0 < FDIM / 4; k0 += 64) {
    WRITEB2();
    STAGEA2(k0);
    __syncthreads();
    if (k0 + 64 < FDIM / 4) LOADB2(k0 + 64);
#pragma unroll
    for (int kk = 0; kk < 2; ++kk) {
      int kc8 = kk * 4 + (lane >> 4);
      bf16x8 a[4], b[4];
#pragma unroll
      for (int m = 0; m < 4; ++m) {
        int row = wm * 64 + m * 16 + (lane & 15);
        a[m] = *reinterpret_cast<const bf16x8*>(&sA[row * 64 + ((kc8 ^ (row & 7)) * 8)]);
      }
#pragma unroll
      for (int n = 0; n < 4; ++n) {
        int col = wn * 64 + n * 16 + (lane & 15);
        b[n] = *reinterpret_cast<const bf16x8*>(&sB[col * 64 + ((kc8 ^ SBW(col)) * 8)]);
      }
#pragma unroll
      for (int m = 0; m < 4; ++m)
#pragma unroll
        for (int n = 0; n < 4; ++n)
          acc[m][n] = __builtin_amdgcn_mfma_f32_16x16x32_bf16(a[m], b[n], acc[m][n], 0, 0, 0);
    }
    __syncthreads();
  }
  unsigned short* yb = y + (size_t)sp * ROWS * DDIM;
#pragma unroll
  for (int m = 0; m < 4; ++m)
#pragma unroll
    for (int j = 0; j < 4; ++j) {
      int rloc = wm * 64 + m * 16 + (lane >> 4) * 4 + j;
      int s = r0 + rloc;
      if (s < cn) {
        unsigned short* orow = yb + (size_t)(off + s) * DDIM + n0 + wn * 64 + (lane & 15);
#pragma unroll
        for (int n = 0; n < 4; ++n) orow[n * 16] = f2b(acc[m][n][j]);
      }
    }
}

// ------- combine: out[t] = p0*sum4(y[.][g0]) + p1*sum4(y[.][g1]) ------------
__global__ void combine_kernel(const unsigned short* __restrict__ y,
                               const int* __restrict__ cnt, const int* __restrict__ tsl,
                               const float* __restrict__ prb, float* __restrict__ out) {
  const int t = blockIdx.x;
  int pre[NEXP];
  pre[0] = 0;
#pragma unroll
  for (int i = 1; i < NEXP; ++i) pre[i] = pre[i - 1] + cnt[i - 1];
  int a = tsl[t * 2], b = tsl[t * 2 + 1];
  int ea = a >> 11, sa = a & (T_TOK - 1);
  int eb = b >> 11, sb = b & (T_TOK - 1);
  size_t ga = (size_t)(pre[ea] + sa) * DDIM;
  size_t gb = (size_t)(pre[eb] + sb) * DDIM;
  float pa = prb[a], pb = prb[b];
  int c = threadIdx.x * 4;
  float sA0 = 0.f, sA1 = 0.f, sA2 = 0.f, sA3 = 0.f;
  float sB0 = 0.f, sB1 = 0.f, sB2 = 0.f, sB3 = 0.f;
#pragma unroll
  for (int sp = 0; sp < 4; ++sp) {
    const unsigned short* yb = y + (size_t)sp * ROWS * DDIM;
    uint2 va = *reinterpret_cast<const uint2*>(yb + ga + c);
    uint2 vb = *reinterpret_cast<const uint2*>(yb + gb + c);
    sA0 += b2f((unsigned short)(va.x & 0xFFFF));
    sA1 += b2f((unsigned short)(va.x >> 16));
    sA2 += b2f((unsigned short)(va.y & 0xFFFF));
    sA3 += b2f((unsigned short)(va.y >> 16));
    sB0 += b2f((unsigned short)(vb.x & 0xFFFF));
    sB1 += b2f((unsigned short)(vb.x >> 16));
    sB2 += b2f((unsigned short)(vb.y & 0xFFFF));
    sB3 += b2f((unsigned short)(vb.y >> 16));
  }
  float4 o;
  o.x = pa * sA0 + pb * sB0;
  o.y = pa * sA1 + pb * sB1;
  o.z = pa * sA2 + pb * sB2;
  o.w = pa * sA3 + pb * sB3;
  *reinterpret_cast<float4*>(out + (size_t)t * DDIM + c) = o;
}

// ============================================================================
extern "C" void kernel_launch(void* const* d_in, const int* in_sizes, int n_in,
                              void* d_out, int out_size, void* d_ws, size_t ws_size,
                              hipStream_t stream) {
  const float* x  = (const float*)d_in[0];
  const float* Wr = (const float*)d_in[1];
  const float* W1 = (const float*)d_in[2];
  const float* W2 = (const float*)d_in[3];
  const float* W3 = (const float*)d_in[4];
  float* out = (float*)d_out;

  char* ws = (char*)d_ws;
  int*   cnt = (int*)ws;                      // 32 B
  int*   tok = (int*)(ws + 1024);             // 64 KB
  float* prb = (float*)(ws + 1024 + 65536);   // 64 KB
  int*   tsl = (int*)(ws + 1024 + 2 * 65536); // 16 KB
  unsigned short* xg  = (unsigned short*)(ws + 256 * 1024);   // ROWS x DDIM bf16
  unsigned short* act = xg + (size_t)ROWS * DDIM;             // ROWS x FDIM bf16
  unsigned short* y   = act + (size_t)ROWS * FDIM;            // 4 x ROWS x DDIM bf16

  hipMemsetAsync(cnt, 0, NEXP * sizeof(int), stream);

  router_kernel<<<T_TOK / 4, 256, 0, stream>>>(x, Wr, cnt, tok, prb, tsl);
  gather_x_kernel<<<(2 * T_TOK) / 4, 256, 0, stream>>>(x, cnt, tok, xg);
  gemm1ab_kernel<<<dim3(FDIM / 64, 16, NEXP), 256, 0, stream>>>(xg, W1, W3, cnt, act);
  gemm2p_kernel<<<dim3(DDIM / 128, 16, NEXP * 4), 256, 0, stream>>>(act, W2, cnt, y);
  combine_kernel<<<T_TOK, 256, 0, stream>>>(y, cnt, tsl, prb, out);
}